// Round 1
// baseline (470.885 us; speedup 1.0000x reference)
//
#include <hip/hip_runtime.h>
#include <math.h>

#define MDIM 128
#define CDIM 64
#define NKEYS 21844   // sum 4^i, i=1..7
// depth boundaries (key index space): c[d] = sum_{e<d} 4^(e+1)
// {0, 4, 20, 84, 340, 1364, 5460, 21844}

__device__ __forceinline__ int depth_of(int n) {
  if (n < 4)    return 0;
  if (n < 20)   return 1;
  if (n < 84)   return 2;
  if (n < 340)  return 3;
  if (n < 1364) return 4;
  if (n < 5460) return 5;
  return 6;
}

__device__ __forceinline__ void depth_info(int n, int& cLo, int& span) {
  if (n < 4)        { cLo = 0;    span = 4; }
  else if (n < 20)  { cLo = 4;    span = 16; }
  else if (n < 84)  { cLo = 20;   span = 64; }
  else if (n < 340) { cLo = 84;   span = 256; }
  else if (n < 1364){ cLo = 340;  span = 1024; }
  else if (n < 5460){ cLo = 1364; span = 4096; }
  else              { cLo = 5460; span = 16384; }
}

// ---------------------------------------------------------------------------
// K1: keys[n][m] = relu(bk[d][m] + dot(states[n][:], Wk[d][m][:]))
// one block per 4 consecutive rows (depth boundaries are all multiples of 4)
// ---------------------------------------------------------------------------
__global__ __launch_bounds__(128) void k_keys(const float* __restrict__ states,
                                              const float* __restrict__ Wk,
                                              const float* __restrict__ bk,
                                              float* __restrict__ keys) {
  __shared__ __align__(16) float sS[4][MDIM];
  const int n0 = blockIdx.x * 4;
  const int m  = threadIdx.x;  // 0..127
  for (int idx = m; idx < 4 * MDIM; idx += 128)
    sS[idx >> 7][idx & 127] = states[(size_t)n0 * MDIM + idx];
  __syncthreads();
  const int d = depth_of(n0);
  const float4* wrow = (const float4*)(Wk + ((size_t)d * MDIM + m) * MDIM);
  float acc0 = 0.f, acc1 = 0.f, acc2 = 0.f, acc3 = 0.f;
#pragma unroll 8
  for (int kq = 0; kq < MDIM / 4; ++kq) {
    float4 w = wrow[kq];
    float4 a = *(const float4*)&sS[0][kq * 4];
    float4 b = *(const float4*)&sS[1][kq * 4];
    float4 c = *(const float4*)&sS[2][kq * 4];
    float4 e = *(const float4*)&sS[3][kq * 4];
    acc0 += w.x * a.x + w.y * a.y + w.z * a.z + w.w * a.w;
    acc1 += w.x * b.x + w.y * b.y + w.z * b.z + w.w * b.w;
    acc2 += w.x * c.x + w.y * c.y + w.z * c.z + w.w * c.w;
    acc3 += w.x * e.x + w.y * e.y + w.z * e.z + w.w * e.w;
  }
  const float bias = bk[d * MDIM + m];
  keys[(size_t)(n0 + 0) * MDIM + m] = fmaxf(acc0 + bias, 0.f);
  keys[(size_t)(n0 + 1) * MDIM + m] = fmaxf(acc1 + bias, 0.f);
  keys[(size_t)(n0 + 2) * MDIM + m] = fmaxf(acc2 + bias, 0.f);
  keys[(size_t)(n0 + 3) * MDIM + m] = fmaxf(acc3 + bias, 0.f);
}

// ---------------------------------------------------------------------------
// K2: query[b][m] = bq[m] + dot(hidden[b][:64], Wq[m][:64])
// ---------------------------------------------------------------------------
__global__ __launch_bounds__(128) void k_query(const float* __restrict__ hidden,
                                               const float* __restrict__ Wq,
                                               const float* __restrict__ bq,
                                               float* __restrict__ query) {
  __shared__ __align__(16) float sH[4][CDIM];
  const int b0 = blockIdx.x * 4;
  const int m  = threadIdx.x;
  for (int idx = m; idx < 4 * CDIM; idx += 128)
    sH[idx >> 6][idx & 63] = hidden[(size_t)b0 * CDIM + idx];
  __syncthreads();
  const float4* wrow = (const float4*)(Wq + (size_t)m * CDIM);
  float acc0 = 0.f, acc1 = 0.f, acc2 = 0.f, acc3 = 0.f;
#pragma unroll
  for (int kq = 0; kq < CDIM / 4; ++kq) {
    float4 w = wrow[kq];
    float4 a = *(const float4*)&sH[0][kq * 4];
    float4 b = *(const float4*)&sH[1][kq * 4];
    float4 c = *(const float4*)&sH[2][kq * 4];
    float4 e = *(const float4*)&sH[3][kq * 4];
    acc0 += w.x * a.x + w.y * a.y + w.z * a.z + w.w * a.w;
    acc1 += w.x * b.x + w.y * b.y + w.z * b.z + w.w * b.w;
    acc2 += w.x * c.x + w.y * c.y + w.z * c.z + w.w * c.w;
    acc3 += w.x * e.x + w.y * e.y + w.z * e.z + w.w * e.w;
  }
  const float bias = bq[m];
  query[(size_t)(b0 + 0) * MDIM + m] = acc0 + bias;
  query[(size_t)(b0 + 1) * MDIM + m] = acc1 + bias;
  query[(size_t)(b0 + 2) * MDIM + m] = acc2 + bias;
  query[(size_t)(b0 + 3) * MDIM + m] = acc3 + bias;
}

// ---------------------------------------------------------------------------
// K3: scores GEMM (64 keys x 64 batch tile, K=128 fully staged) fused with
// group-of-4 log-softmax; writes logp directly into d_out at per-depth
// offsets. If addParent!=0 (depth-7 pass), also adds the (already
// accumulated) depth-6 parent value -> final output for depth 7.
// ---------------------------------------------------------------------------
__global__ __launch_bounds__(256) void k_scores(const float* __restrict__ keys,
                                                const float* __restrict__ query,
                                                float* __restrict__ out,
                                                int keyLo, int keyHi, int B,
                                                int addParent) {
  __shared__ __align__(16) float kS[MDIM][64];
  __shared__ __align__(16) float qS[MDIM][64];
  const int tid = threadIdx.x;
  const int n0  = keyLo + blockIdx.x * 64;
  const int b0  = blockIdx.y * 64;
  const int rl  = tid & 63;   // row within tile
  const int kq4 = tid >> 6;   // 0..3: float4-column group

  {  // stage keys tile (transposed: kS[k][n_local]); zero-pad past keyHi
    const int n = n0 + rl;
    const bool ok = (n < keyHi);
    const float4* src = (const float4*)(keys + (size_t)n * MDIM);
#pragma unroll
    for (int s = 0; s < 8; ++s) {
      const int kidx = kq4 + s * 4;  // float4 index 0..31
      float4 v = ok ? src[kidx] : make_float4(0.f, 0.f, 0.f, 0.f);
      const int k = kidx * 4;
      kS[k + 0][rl] = v.x; kS[k + 1][rl] = v.y;
      kS[k + 2][rl] = v.z; kS[k + 3][rl] = v.w;
    }
  }
  {  // stage query tile (transposed)
    const float4* src = (const float4*)(query + (size_t)(b0 + rl) * MDIM);
#pragma unroll
    for (int s = 0; s < 8; ++s) {
      const int kidx = kq4 + s * 4;
      float4 v = src[kidx];
      const int k = kidx * 4;
      qS[k + 0][rl] = v.x; qS[k + 1][rl] = v.y;
      qS[k + 2][rl] = v.z; qS[k + 3][rl] = v.w;
    }
  }
  __syncthreads();

  const int ti = tid & 15;   // key quad (4 consecutive keys = one sibling group)
  const int tj = tid >> 4;   // batch quad
  float acc[4][4] = {};
#pragma unroll 8
  for (int k = 0; k < MDIM; ++k) {
    const float4 kv = *(const float4*)&kS[k][ti * 4];
    const float4 qv = *(const float4*)&qS[k][tj * 4];
    acc[0][0] += kv.x * qv.x; acc[0][1] += kv.x * qv.y;
    acc[0][2] += kv.x * qv.z; acc[0][3] += kv.x * qv.w;
    acc[1][0] += kv.y * qv.x; acc[1][1] += kv.y * qv.y;
    acc[1][2] += kv.y * qv.z; acc[1][3] += kv.y * qv.w;
    acc[2][0] += kv.z * qv.x; acc[2][1] += kv.z * qv.y;
    acc[2][2] += kv.z * qv.z; acc[2][3] += kv.z * qv.w;
    acc[3][0] += kv.w * qv.x; acc[3][1] += kv.w * qv.y;
    acc[3][2] += kv.w * qv.z; acc[3][3] += kv.w * qv.w;
  }

  const int n = n0 + ti * 4;  // group base key (aligned to 4)
  if (n < keyHi) {
    int cLo, span;
    depth_info(n, cLo, span);
    const size_t regionBase = (size_t)B * cLo;
#pragma unroll
    for (int jj = 0; jj < 4; ++jj) {
      const int b = b0 + tj * 4 + jj;
      const float s0 = acc[0][jj], s1 = acc[1][jj];
      const float s2 = acc[2][jj], s3 = acc[3][jj];
      const float mx = fmaxf(fmaxf(s0, s1), fmaxf(s2, s3));
      const float lse = mx + logf(expf(s0 - mx) + expf(s1 - mx) +
                                  expf(s2 - mx) + expf(s3 - mx));
      float par = 0.f;
      if (addParent)  // depth-6 (0-based) keys: parent = accumulated depth-5 out
        par = out[(size_t)B * 1364 + (size_t)b * 4096 + ((n >> 2) - 1365)];
      const size_t base = regionBase + (size_t)b * span + (n - cLo);
      out[base + 0] = s0 - lse + par;
      out[base + 1] = s1 - lse + par;
      out[base + 2] = s2 - lse + par;
      out[base + 3] = s3 - lse + par;
    }
  }
}

// ---------------------------------------------------------------------------
// K4: in-place cumulative tree accumulation for depths 2..6 (0-based i=1..5).
// One block per batch element; running cum kept in LDS (<=1024 parents).
// ---------------------------------------------------------------------------
__global__ __launch_bounds__(256) void k_accum(float* __restrict__ out, int B) {
  __shared__ float bufA[1024];
  __shared__ float bufB[1024];
  const int b = blockIdx.x;
  const int t = threadIdx.x;
  const int cArr[6] = {0, 4, 20, 84, 340, 1364};
  if (t < 4) bufA[t] = out[(size_t)b * 4 + t];
  __syncthreads();
  float* prev = bufA;
  float* next = bufB;
#pragma unroll
  for (int i = 1; i <= 5; ++i) {
    const int span = 4 << (2 * i);  // 4^(i+1)
    const size_t base = (size_t)B * cArr[i] + (size_t)b * span;
    for (int j = t; j < span; j += 256) {
      const float v = out[base + j] + prev[j >> 2];
      out[base + j] = v;
      if (i < 5) next[j] = v;   // i==5 cum (4096) not needed in LDS
    }
    __syncthreads();
    float* tmp = prev; prev = next; next = tmp;
  }
}

// ---------------------------------------------------------------------------
extern "C" void kernel_launch(void* const* d_in, const int* in_sizes, int n_in,
                              void* d_out, int out_size, void* d_ws, size_t ws_size,
                              hipStream_t stream) {
  const float* hidden = (const float*)d_in[0];
  const float* Wq     = (const float*)d_in[1];
  const float* bq     = (const float*)d_in[2];
  const float* states = (const float*)d_in[3];
  const float* Wk     = (const float*)d_in[4];
  const float* bk     = (const float*)d_in[5];
  float* out = (float*)d_out;
  const int B = in_sizes[0] / CDIM;  // 4096

  float* keys  = (float*)d_ws;                    // NKEYS*128 f32 = 11.2 MB
  float* query = keys + (size_t)NKEYS * MDIM;     // B*128 f32 = 2 MB

  k_keys<<<NKEYS / 4, 128, 0, stream>>>(states, Wk, bk, keys);
  k_query<<<B / 4, 128, 0, stream>>>(hidden, Wq, bq, query);

  // depths 1..6 (keys 0..5460): logp written to out
  dim3 gA((5460 + 63) / 64, B / 64);
  k_scores<<<gA, 256, 0, stream>>>(keys, query, out, 0, 5460, B, 0);

  // accumulate depths 2..6 in-place (out_6 region becomes final cum)
  k_accum<<<B, 256, 0, stream>>>(out, B);

  // depth 7 (keys 5460..21844): logp + accumulated parent -> final out
  dim3 gB(16384 / 64, B / 64);
  k_scores<<<gB, 256, 0, stream>>>(keys, query, out, 5460, NKEYS, B, 1);
}

// Round 2
// 280.033 us; speedup vs baseline: 1.6815x; 1.6815x over previous
//
#include <hip/hip_runtime.h>
#include <hip/hip_bf16.h>
#include <math.h>

#define MDIM 128
#define CDIM 64
#define NKEYS 21844   // sum 4^i, i=1..7
// depth boundaries (key index space): {0, 4, 20, 84, 340, 1364, 5460, 21844}

typedef __attribute__((ext_vector_type(8))) __bf16 bf16x8;
typedef __attribute__((ext_vector_type(4))) float f32x4;

__device__ __forceinline__ int depth_of(int n) {
  if (n < 4)    return 0;
  if (n < 20)   return 1;
  if (n < 84)   return 2;
  if (n < 340)  return 3;
  if (n < 1364) return 4;
  if (n < 5460) return 5;
  return 6;
}

__device__ __forceinline__ void depth_info(int n, int& cLo, int& span) {
  if (n < 4)        { cLo = 0;    span = 4; }
  else if (n < 20)  { cLo = 4;    span = 16; }
  else if (n < 84)  { cLo = 20;   span = 64; }
  else if (n < 340) { cLo = 84;   span = 256; }
  else if (n < 1364){ cLo = 340;  span = 1024; }
  else if (n < 5460){ cLo = 1364; span = 4096; }
  else              { cLo = 5460; span = 16384; }
}

// ---------------------------------------------------------------------------
// K1: keys[n][m] = relu(bk[d][m] + dot(states[n][:], Wk[d][m][:]))  -> bf16
// ---------------------------------------------------------------------------
__global__ __launch_bounds__(128) void k_keys(const float* __restrict__ states,
                                              const float* __restrict__ Wk,
                                              const float* __restrict__ bk,
                                              __hip_bfloat16* __restrict__ keys) {
  __shared__ __align__(16) float sS[4][MDIM];
  const int n0 = blockIdx.x * 4;
  const int m  = threadIdx.x;  // 0..127
  for (int idx = m; idx < 4 * MDIM; idx += 128)
    sS[idx >> 7][idx & 127] = states[(size_t)n0 * MDIM + idx];
  __syncthreads();
  const int d = depth_of(n0);
  const float4* wrow = (const float4*)(Wk + ((size_t)d * MDIM + m) * MDIM);
  float acc0 = 0.f, acc1 = 0.f, acc2 = 0.f, acc3 = 0.f;
#pragma unroll 8
  for (int kq = 0; kq < MDIM / 4; ++kq) {
    float4 w = wrow[kq];
    float4 a = *(const float4*)&sS[0][kq * 4];
    float4 b = *(const float4*)&sS[1][kq * 4];
    float4 c = *(const float4*)&sS[2][kq * 4];
    float4 e = *(const float4*)&sS[3][kq * 4];
    acc0 += w.x * a.x + w.y * a.y + w.z * a.z + w.w * a.w;
    acc1 += w.x * b.x + w.y * b.y + w.z * b.z + w.w * b.w;
    acc2 += w.x * c.x + w.y * c.y + w.z * c.z + w.w * c.w;
    acc3 += w.x * e.x + w.y * e.y + w.z * e.z + w.w * e.w;
  }
  const float bias = bk[d * MDIM + m];
  keys[(size_t)(n0 + 0) * MDIM + m] = __float2bfloat16(fmaxf(acc0 + bias, 0.f));
  keys[(size_t)(n0 + 1) * MDIM + m] = __float2bfloat16(fmaxf(acc1 + bias, 0.f));
  keys[(size_t)(n0 + 2) * MDIM + m] = __float2bfloat16(fmaxf(acc2 + bias, 0.f));
  keys[(size_t)(n0 + 3) * MDIM + m] = __float2bfloat16(fmaxf(acc3 + bias, 0.f));
}

// ---------------------------------------------------------------------------
// K2: query[b][m] = bq[m] + dot(hidden[b][:64], Wq[m][:64])  -> bf16
// ---------------------------------------------------------------------------
__global__ __launch_bounds__(128) void k_query(const float* __restrict__ hidden,
                                               const float* __restrict__ Wq,
                                               const float* __restrict__ bq,
                                               __hip_bfloat16* __restrict__ query) {
  __shared__ __align__(16) float sH[4][CDIM];
  const int b0 = blockIdx.x * 4;
  const int m  = threadIdx.x;
  for (int idx = m; idx < 4 * CDIM; idx += 128)
    sH[idx >> 6][idx & 63] = hidden[(size_t)b0 * CDIM + idx];
  __syncthreads();
  const float4* wrow = (const float4*)(Wq + (size_t)m * CDIM);
  float acc0 = 0.f, acc1 = 0.f, acc2 = 0.f, acc3 = 0.f;
#pragma unroll
  for (int kq = 0; kq < CDIM / 4; ++kq) {
    float4 w = wrow[kq];
    float4 a = *(const float4*)&sH[0][kq * 4];
    float4 b = *(const float4*)&sH[1][kq * 4];
    float4 c = *(const float4*)&sH[2][kq * 4];
    float4 e = *(const float4*)&sH[3][kq * 4];
    acc0 += w.x * a.x + w.y * a.y + w.z * a.z + w.w * a.w;
    acc1 += w.x * b.x + w.y * b.y + w.z * b.z + w.w * b.w;
    acc2 += w.x * c.x + w.y * c.y + w.z * c.z + w.w * c.w;
    acc3 += w.x * e.x + w.y * e.y + w.z * e.z + w.w * e.w;
  }
  const float bias = bq[m];
  query[(size_t)(b0 + 0) * MDIM + m] = __float2bfloat16(acc0 + bias);
  query[(size_t)(b0 + 1) * MDIM + m] = __float2bfloat16(acc1 + bias);
  query[(size_t)(b0 + 2) * MDIM + m] = __float2bfloat16(acc2 + bias);
  query[(size_t)(b0 + 3) * MDIM + m] = __float2bfloat16(acc3 + bias);
}

// ---------------------------------------------------------------------------
// K3: MFMA scores GEMM + fused group-of-4 log-softmax (+ parent add).
// Block = 4 waves; block tile = 64 keys x 128 batch; wave tile = 32 x 64.
// Fragments loaded straight from global (L2-resident bf16 keys/query):
//   A/B layout for mfma_f32_16x16x32_bf16: row/col = lane&15,
//   k = (lane>>4)*8 + [0..7]  -> one 16B load per fragment.
// C/D layout: col(b) = lane&15, row(key) = (lane>>4)*4 + reg -> each lane's
// 4 accumulator regs are exactly one sibling quad -> thread-local softmax.
// ---------------------------------------------------------------------------
template <int ADD_PARENT>
__global__ __launch_bounds__(256) void k_scores(const __hip_bfloat16* __restrict__ keys,
                                                const __hip_bfloat16* __restrict__ query,
                                                float* __restrict__ out,
                                                int keyLo, int keyHi, int B) {
  const int tid  = threadIdx.x;
  const int lane = tid & 63;
  const int w    = tid >> 6;
  const int wr   = w & 1;       // key half
  const int wc   = w >> 1;      // batch half
  const int lr   = lane & 15;
  const int lk   = lane >> 4;   // 0..3

  const int n_base = keyLo + blockIdx.x * 64 + wr * 32;
  const int b_base = blockIdx.y * 128 + wc * 64;

  const bf16x8* krow0 = reinterpret_cast<const bf16x8*>(keys + (size_t)(n_base + lr) * MDIM);
  const bf16x8* krow1 = reinterpret_cast<const bf16x8*>(keys + (size_t)(n_base + 16 + lr) * MDIM);
  const bf16x8* qrow0 = reinterpret_cast<const bf16x8*>(query + (size_t)(b_base +  0 + lr) * MDIM);
  const bf16x8* qrow1 = reinterpret_cast<const bf16x8*>(query + (size_t)(b_base + 16 + lr) * MDIM);
  const bf16x8* qrow2 = reinterpret_cast<const bf16x8*>(query + (size_t)(b_base + 32 + lr) * MDIM);
  const bf16x8* qrow3 = reinterpret_cast<const bf16x8*>(query + (size_t)(b_base + 48 + lr) * MDIM);

  f32x4 acc[2][4] = {};
#pragma unroll
  for (int kf = 0; kf < 4; ++kf) {
    const int fi = kf * 4 + lk;   // element offset (kf*32 + lk*8) / 8
    bf16x8 a0 = krow0[fi];
    bf16x8 a1 = krow1[fi];
    bf16x8 b0 = qrow0[fi];
    bf16x8 b1 = qrow1[fi];
    bf16x8 b2 = qrow2[fi];
    bf16x8 b3 = qrow3[fi];
    acc[0][0] = __builtin_amdgcn_mfma_f32_16x16x32_bf16(a0, b0, acc[0][0], 0, 0, 0);
    acc[0][1] = __builtin_amdgcn_mfma_f32_16x16x32_bf16(a0, b1, acc[0][1], 0, 0, 0);
    acc[0][2] = __builtin_amdgcn_mfma_f32_16x16x32_bf16(a0, b2, acc[0][2], 0, 0, 0);
    acc[0][3] = __builtin_amdgcn_mfma_f32_16x16x32_bf16(a0, b3, acc[0][3], 0, 0, 0);
    acc[1][0] = __builtin_amdgcn_mfma_f32_16x16x32_bf16(a1, b0, acc[1][0], 0, 0, 0);
    acc[1][1] = __builtin_amdgcn_mfma_f32_16x16x32_bf16(a1, b1, acc[1][1], 0, 0, 0);
    acc[1][2] = __builtin_amdgcn_mfma_f32_16x16x32_bf16(a1, b2, acc[1][2], 0, 0, 0);
    acc[1][3] = __builtin_amdgcn_mfma_f32_16x16x32_bf16(a1, b3, acc[1][3], 0, 0, 0);
  }

#pragma unroll
  for (int m = 0; m < 2; ++m) {
    const int nq = n_base + m * 16 + lk * 4;  // sibling-quad base key
    if (nq >= keyHi) continue;
    int cLo, span;
    depth_info(nq, cLo, span);
    const size_t regionBase = (size_t)B * cLo + (size_t)(nq - cLo);
#pragma unroll
    for (int j = 0; j < 4; ++j) {
      const int b = b_base + j * 16 + lr;
      const f32x4 s = acc[m][j];
      const float mx = fmaxf(fmaxf(s[0], s[1]), fmaxf(s[2], s[3]));
      const float lse = mx + __logf(__expf(s[0] - mx) + __expf(s[1] - mx) +
                                    __expf(s[2] - mx) + __expf(s[3] - mx));
      float par = 0.f;
      if (ADD_PARENT)
        par = out[(size_t)B * 1364 + (size_t)b * 4096 + ((nq >> 2) - 1365)];
      float4 o;
      o.x = s[0] - lse + par;
      o.y = s[1] - lse + par;
      o.z = s[2] - lse + par;
      o.w = s[3] - lse + par;
      *reinterpret_cast<float4*>(out + regionBase + (size_t)b * span) = o;
    }
  }
}

// ---------------------------------------------------------------------------
// K4: in-place cumulative tree accumulation for depths 2..6 (0-based i=1..5).
// ---------------------------------------------------------------------------
__global__ __launch_bounds__(256) void k_accum(float* __restrict__ out, int B) {
  __shared__ float bufA[1024];
  __shared__ float bufB[1024];
  const int b = blockIdx.x;
  const int t = threadIdx.x;
  const int cArr[6] = {0, 4, 20, 84, 340, 1364};
  if (t < 4) bufA[t] = out[(size_t)b * 4 + t];
  __syncthreads();
  float* prev = bufA;
  float* next = bufB;
#pragma unroll
  for (int i = 1; i <= 5; ++i) {
    const int span = 4 << (2 * i);  // 4^(i+1)
    const size_t base = (size_t)B * cArr[i] + (size_t)b * span;
    for (int j = t; j < span; j += 256) {
      const float v = out[base + j] + prev[j >> 2];
      out[base + j] = v;
      if (i < 5) next[j] = v;
    }
    __syncthreads();
    float* tmp = prev; prev = next; next = tmp;
  }
}

// ---------------------------------------------------------------------------
extern "C" void kernel_launch(void* const* d_in, const int* in_sizes, int n_in,
                              void* d_out, int out_size, void* d_ws, size_t ws_size,
                              hipStream_t stream) {
  const float* hidden = (const float*)d_in[0];
  const float* Wq     = (const float*)d_in[1];
  const float* bq     = (const float*)d_in[2];
  const float* states = (const float*)d_in[3];
  const float* Wk     = (const float*)d_in[4];
  const float* bk     = (const float*)d_in[5];
  float* out = (float*)d_out;
  const int B = in_sizes[0] / CDIM;  // 4096

  __hip_bfloat16* keys  = (__hip_bfloat16*)d_ws;            // NKEYS*128 bf16 = 5.6 MB
  __hip_bfloat16* query = keys + (size_t)NKEYS * MDIM;      // B*128 bf16 = 1 MB

  k_keys<<<NKEYS / 4, 128, 0, stream>>>(states, Wk, bk, keys);
  k_query<<<B / 4, 128, 0, stream>>>(hidden, Wq, bq, query);

  // depths 1..6 (keys 0..5460): logp written to out
  dim3 gA((5460 + 63) / 64, B / 128);
  k_scores<0><<<gA, 256, 0, stream>>>(keys, query, out, 0, 5460, B);

  // accumulate depths 2..6 in-place (depth-6 region becomes final cum)
  k_accum<<<B, 256, 0, stream>>>(out, B);

  // depth 7 (keys 5460..21844): logp + accumulated parent -> final out
  dim3 gB(16384 / 64, B / 128);
  k_scores<1><<<gB, 256, 0, stream>>>(keys, query, out, 5460, NKEYS, B);
}

// Round 3
// 241.577 us; speedup vs baseline: 1.9492x; 1.1592x over previous
//
#include <hip/hip_runtime.h>
#include <hip/hip_bf16.h>
#include <math.h>

#define MDIM 128
#define CDIM 64
#define NKEYS 21844   // sum 4^i, i=1..7
// layer key offsets: c1=0 c2=4 c3=20 c4=84 c5=340 c6=1364 c7=5460

typedef __attribute__((ext_vector_type(8))) __bf16 bf16x8;
typedef __attribute__((ext_vector_type(4))) float f32x4;

__device__ __forceinline__ int depth_of(int n) {
  if (n < 4)    return 0;
  if (n < 20)   return 1;
  if (n < 84)   return 2;
  if (n < 340)  return 3;
  if (n < 1364) return 4;
  if (n < 5460) return 5;
  return 6;
}

// ---------------------------------------------------------------------------
// K1: keys[n][m] = relu(bk[d][m] + dot(states[n][:], Wk[d][m][:]))  -> bf16
// ---------------------------------------------------------------------------
__global__ __launch_bounds__(128) void k_keys(const float* __restrict__ states,
                                              const float* __restrict__ Wk,
                                              const float* __restrict__ bk,
                                              __hip_bfloat16* __restrict__ keys) {
  __shared__ __align__(16) float sS[4][MDIM];
  const int n0 = blockIdx.x * 4;
  const int m  = threadIdx.x;  // 0..127
  for (int idx = m; idx < 4 * MDIM; idx += 128)
    sS[idx >> 7][idx & 127] = states[(size_t)n0 * MDIM + idx];
  __syncthreads();
  const int d = depth_of(n0);
  const float4* wrow = (const float4*)(Wk + ((size_t)d * MDIM + m) * MDIM);
  float acc0 = 0.f, acc1 = 0.f, acc2 = 0.f, acc3 = 0.f;
#pragma unroll 8
  for (int kq = 0; kq < MDIM / 4; ++kq) {
    float4 w = wrow[kq];
    float4 a = *(const float4*)&sS[0][kq * 4];
    float4 b = *(const float4*)&sS[1][kq * 4];
    float4 c = *(const float4*)&sS[2][kq * 4];
    float4 e = *(const float4*)&sS[3][kq * 4];
    acc0 += w.x * a.x + w.y * a.y + w.z * a.z + w.w * a.w;
    acc1 += w.x * b.x + w.y * b.y + w.z * b.z + w.w * b.w;
    acc2 += w.x * c.x + w.y * c.y + w.z * c.z + w.w * c.w;
    acc3 += w.x * e.x + w.y * e.y + w.z * e.z + w.w * e.w;
  }
  const float bias = bk[d * MDIM + m];
  keys[(size_t)(n0 + 0) * MDIM + m] = __float2bfloat16(fmaxf(acc0 + bias, 0.f));
  keys[(size_t)(n0 + 1) * MDIM + m] = __float2bfloat16(fmaxf(acc1 + bias, 0.f));
  keys[(size_t)(n0 + 2) * MDIM + m] = __float2bfloat16(fmaxf(acc2 + bias, 0.f));
  keys[(size_t)(n0 + 3) * MDIM + m] = __float2bfloat16(fmaxf(acc3 + bias, 0.f));
}

// ---------------------------------------------------------------------------
// K2: query[b][m] = bq[m] + dot(hidden[b][:64], Wq[m][:64])  -> bf16
// ---------------------------------------------------------------------------
__global__ __launch_bounds__(128) void k_query(const float* __restrict__ hidden,
                                               const float* __restrict__ Wq,
                                               const float* __restrict__ bq,
                                               __hip_bfloat16* __restrict__ query) {
  __shared__ __align__(16) float sH[4][CDIM];
  const int b0 = blockIdx.x * 4;
  const int m  = threadIdx.x;
  for (int idx = m; idx < 4 * CDIM; idx += 128)
    sH[idx >> 6][idx & 63] = hidden[(size_t)b0 * CDIM + idx];
  __syncthreads();
  const float4* wrow = (const float4*)(Wq + (size_t)m * CDIM);
  float acc0 = 0.f, acc1 = 0.f, acc2 = 0.f, acc3 = 0.f;
#pragma unroll
  for (int kq = 0; kq < CDIM / 4; ++kq) {
    float4 w = wrow[kq];
    float4 a = *(const float4*)&sH[0][kq * 4];
    float4 b = *(const float4*)&sH[1][kq * 4];
    float4 c = *(const float4*)&sH[2][kq * 4];
    float4 e = *(const float4*)&sH[3][kq * 4];
    acc0 += w.x * a.x + w.y * a.y + w.z * a.z + w.w * a.w;
    acc1 += w.x * b.x + w.y * b.y + w.z * b.z + w.w * b.w;
    acc2 += w.x * c.x + w.y * c.y + w.z * c.z + w.w * c.w;
    acc3 += w.x * e.x + w.y * e.y + w.z * e.z + w.w * e.w;
  }
  const float bias = bq[m];
  query[(size_t)(b0 + 0) * MDIM + m] = __float2bfloat16(acc0 + bias);
  query[(size_t)(b0 + 1) * MDIM + m] = __float2bfloat16(acc1 + bias);
  query[(size_t)(b0 + 2) * MDIM + m] = __float2bfloat16(acc2 + bias);
  query[(size_t)(b0 + 3) * MDIM + m] = __float2bfloat16(acc3 + bias);
}

// ---------------------------------------------------------------------------
// K3: fused tree walk. One wave = one depth-4 subtree x one 16-b tile.
// MFMA with A=query, B=keys -> D[row=b, col=key]:
//   lane = hi*16 + c;  c = key col (0..15), regs j=0..3 -> b = hi*4+j.
// Group-of-4 log-softmax = 4-lane shfl_xor butterfly over c&3.
// Parent chain kept in registers: child tile 4T+u's parent for col c is the
// parent tile's col 4u + (c>>2), same b -> one shfl per reg.
// Stores: 16 consecutive keys per 16-lane group = 64B segments, coalesced.
// ---------------------------------------------------------------------------
__device__ __forceinline__ f32x4 tile_scores(const __hip_bfloat16* __restrict__ keys,
                                             int keyBase, const bf16x8 qf[4],
                                             int c, int hi) {
  const bf16x8* krow = reinterpret_cast<const bf16x8*>(keys + (size_t)(keyBase + c) * MDIM);
  f32x4 acc = {};
#pragma unroll
  for (int kf = 0; kf < 4; ++kf) {
    bf16x8 kfrag = krow[kf * 4 + hi];
    acc = __builtin_amdgcn_mfma_f32_16x16x32_bf16(qf[kf], kfrag, acc, 0, 0, 0);
  }
  return acc;
}

__device__ __forceinline__ f32x4 quad_logp(f32x4 s) {
  f32x4 r;
#pragma unroll
  for (int j = 0; j < 4; ++j) {
    float v = s[j];
    float m = fmaxf(v, __shfl_xor(v, 1, 64));
    m = fmaxf(m, __shfl_xor(m, 2, 64));
    float e = __expf(v - m);
    float t = e + __shfl_xor(e, 1, 64);
    t += __shfl_xor(t, 2, 64);
    r[j] = v - m - __logf(t);
  }
  return r;
}

__device__ __forceinline__ f32x4 gather_parent(f32x4 cum, int u, int lane) {
  const int src = (lane & 48) | (u * 4) | ((lane & 15) >> 2);
  f32x4 r;
#pragma unroll
  for (int j = 0; j < 4; ++j) r[j] = __shfl(cum[j], src, 64);
  return r;
}

__device__ __forceinline__ void store_tile(float* __restrict__ out, int B,
                                           int cLayer, int span, int node0,
                                           int b0, int c, int hi, f32x4 v) {
  float* base = out + (size_t)cLayer * B + (size_t)node0 + c;
#pragma unroll
  for (int j = 0; j < 4; ++j)
    base[(size_t)(b0 + hi * 4 + j) * span] = v[j];
}

__global__ __launch_bounds__(256) void k_tree(const __hip_bfloat16* __restrict__ keys,
                                              const __hip_bfloat16* __restrict__ query,
                                              float* __restrict__ out, int B) {
  const int tid  = threadIdx.x;
  const int lane = tid & 63;
  const int w    = tid >> 6;
  const int bt   = blockIdx.x >> 2;
  const int T4   = (blockIdx.x & 3) * 4 + w;   // depth-4 tile 0..15
  const int c    = lane & 15;                  // key col
  const int hi   = lane >> 4;                  // 0..3
  const int b0   = bt * 16;

  // query A-fragments (row = b0 + c ... A-frag row index is lane&15)
  bf16x8 qf[4];
  {
    const bf16x8* qrow = reinterpret_cast<const bf16x8*>(query + (size_t)(b0 + c) * MDIM);
#pragma unroll
    for (int kf = 0; kf < 4; ++kf) qf[kf] = qrow[kf * 4 + hi];
  }

  // ---- depth 1 (keys 0..15; only quad 0 = real depth-1 nodes)
  f32x4 s = tile_scores(keys, 0, qf, c, hi);
  f32x4 cum1 = quad_logp(s);
  if (T4 == 0 && c < 4) {
#pragma unroll
    for (int j = 0; j < 4; ++j)
      out[(size_t)(b0 + hi * 4 + j) * 4 + c] = cum1[j];
  }

  // ---- depth 2 (keys 4..19, nodes 0..15)
  s = tile_scores(keys, 4, qf, c, hi);
  f32x4 cum2 = quad_logp(s) + gather_parent(cum1, 0, lane);
  if (T4 == 0) store_tile(out, B, 4, 16, 0, b0, c, hi, cum2);

  // ---- depth 3 (tile T3 = T4>>2, keys 20+16*T3)
  const int T3 = T4 >> 2;
  s = tile_scores(keys, 20 + 16 * T3, qf, c, hi);
  f32x4 cum3 = quad_logp(s) + gather_parent(cum2, T3, lane);
  if ((T4 & 3) == 0) store_tile(out, B, 20, 64, 16 * T3, b0, c, hi, cum3);

  // ---- depth 4 (tile T4, keys 84+16*T4)
  s = tile_scores(keys, 84 + 16 * T4, qf, c, hi);
  f32x4 cum4 = quad_logp(s) + gather_parent(cum3, T4 & 3, lane);
  store_tile(out, B, 84, 256, 16 * T4, b0, c, hi, cum4);

  // ---- depths 5..7 DFS (cum chain in registers)
#pragma unroll 1
  for (int u4 = 0; u4 < 4; ++u4) {
    const int T5 = T4 * 4 + u4;
    s = tile_scores(keys, 340 + 16 * T5, qf, c, hi);
    f32x4 cum5 = quad_logp(s) + gather_parent(cum4, u4, lane);
    store_tile(out, B, 340, 1024, 16 * T5, b0, c, hi, cum5);
#pragma unroll 1
    for (int u5 = 0; u5 < 4; ++u5) {
      const int T6 = T5 * 4 + u5;
      s = tile_scores(keys, 1364 + 16 * T6, qf, c, hi);
      f32x4 cum6 = quad_logp(s) + gather_parent(cum5, u5, lane);
      store_tile(out, B, 1364, 4096, 16 * T6, b0, c, hi, cum6);
#pragma unroll 1
      for (int u6 = 0; u6 < 4; ++u6) {
        const int T7 = T6 * 4 + u6;
        s = tile_scores(keys, 5460 + 16 * T7, qf, c, hi);
        f32x4 cum7 = quad_logp(s) + gather_parent(cum6, u6, lane);
        store_tile(out, B, 5460, 16384, 16 * T7, b0, c, hi, cum7);
      }
    }
  }
}

// ---------------------------------------------------------------------------
extern "C" void kernel_launch(void* const* d_in, const int* in_sizes, int n_in,
                              void* d_out, int out_size, void* d_ws, size_t ws_size,
                              hipStream_t stream) {
  const float* hidden = (const float*)d_in[0];
  const float* Wq     = (const float*)d_in[1];
  const float* bq     = (const float*)d_in[2];
  const float* states = (const float*)d_in[3];
  const float* Wk     = (const float*)d_in[4];
  const float* bk     = (const float*)d_in[5];
  float* out = (float*)d_out;
  const int B = in_sizes[0] / CDIM;  // 4096

  __hip_bfloat16* keys  = (__hip_bfloat16*)d_ws;        // NKEYS*128 bf16 = 5.6 MB
  __hip_bfloat16* query = keys + (size_t)NKEYS * MDIM;  // B*128 bf16 = 1 MB

  k_keys<<<NKEYS / 4, 128, 0, stream>>>(states, Wk, bk, keys);
  k_query<<<B / 4, 128, 0, stream>>>(hidden, Wq, bq, query);

  // 4096 independent waves: (B/16 btiles) x (16 depth-4 subtrees)
  k_tree<<<(B / 16) * 4, 256, 0, stream>>>(keys, query, out, B);
}

// Round 4
// 154.519 us; speedup vs baseline: 3.0474x; 1.5634x over previous
//
#include <hip/hip_runtime.h>
#include <hip/hip_bf16.h>
#include <math.h>

#define MDIM 128
#define CDIM 64
#define NKEYS 21844   // sum 4^i, i=1..7
// layer key offsets: c1=0 c2=4 c3=20 c4=84 c5=340 c6=1364 c7=5460

typedef __attribute__((ext_vector_type(8))) __bf16 bf16x8;
typedef __attribute__((ext_vector_type(4))) float f32x4;

__device__ __forceinline__ int depth_of(int n) {
  if (n < 4)    return 0;
  if (n < 20)   return 1;
  if (n < 84)   return 2;
  if (n < 340)  return 3;
  if (n < 1364) return 4;
  if (n < 5460) return 5;
  return 6;
}

// ---------------------------------------------------------------------------
// K1: keys[n][m] = relu(bk[d][m] + dot(states[n][:], Wk[d][m][:]))  -> bf16
// ---------------------------------------------------------------------------
__global__ __launch_bounds__(128) void k_keys(const float* __restrict__ states,
                                              const float* __restrict__ Wk,
                                              const float* __restrict__ bk,
                                              __hip_bfloat16* __restrict__ keys) {
  __shared__ __align__(16) float sS[4][MDIM];
  const int n0 = blockIdx.x * 4;
  const int m  = threadIdx.x;  // 0..127
  for (int idx = m; idx < 4 * MDIM; idx += 128)
    sS[idx >> 7][idx & 127] = states[(size_t)n0 * MDIM + idx];
  __syncthreads();
  const int d = depth_of(n0);
  const float4* wrow = (const float4*)(Wk + ((size_t)d * MDIM + m) * MDIM);
  float acc0 = 0.f, acc1 = 0.f, acc2 = 0.f, acc3 = 0.f;
#pragma unroll 8
  for (int kq = 0; kq < MDIM / 4; ++kq) {
    float4 w = wrow[kq];
    float4 a = *(const float4*)&sS[0][kq * 4];
    float4 b = *(const float4*)&sS[1][kq * 4];
    float4 c = *(const float4*)&sS[2][kq * 4];
    float4 e = *(const float4*)&sS[3][kq * 4];
    acc0 += w.x * a.x + w.y * a.y + w.z * a.z + w.w * a.w;
    acc1 += w.x * b.x + w.y * b.y + w.z * b.z + w.w * b.w;
    acc2 += w.x * c.x + w.y * c.y + w.z * c.z + w.w * c.w;
    acc3 += w.x * e.x + w.y * e.y + w.z * e.z + w.w * e.w;
  }
  const float bias = bk[d * MDIM + m];
  keys[(size_t)(n0 + 0) * MDIM + m] = __float2bfloat16(fmaxf(acc0 + bias, 0.f));
  keys[(size_t)(n0 + 1) * MDIM + m] = __float2bfloat16(fmaxf(acc1 + bias, 0.f));
  keys[(size_t)(n0 + 2) * MDIM + m] = __float2bfloat16(fmaxf(acc2 + bias, 0.f));
  keys[(size_t)(n0 + 3) * MDIM + m] = __float2bfloat16(fmaxf(acc3 + bias, 0.f));
}

// ---------------------------------------------------------------------------
// K2: query[b][m] = bq[m] + dot(hidden[b][:64], Wq[m][:64])  -> bf16
// ---------------------------------------------------------------------------
__global__ __launch_bounds__(128) void k_query(const float* __restrict__ hidden,
                                               const float* __restrict__ Wq,
                                               const float* __restrict__ bq,
                                               __hip_bfloat16* __restrict__ query) {
  __shared__ __align__(16) float sH[4][CDIM];
  const int b0 = blockIdx.x * 4;
  const int m  = threadIdx.x;
  for (int idx = m; idx < 4 * CDIM; idx += 128)
    sH[idx >> 6][idx & 63] = hidden[(size_t)b0 * CDIM + idx];
  __syncthreads();
  const float4* wrow = (const float4*)(Wq + (size_t)m * CDIM);
  float acc0 = 0.f, acc1 = 0.f, acc2 = 0.f, acc3 = 0.f;
#pragma unroll
  for (int kq = 0; kq < CDIM / 4; ++kq) {
    float4 w = wrow[kq];
    float4 a = *(const float4*)&sH[0][kq * 4];
    float4 b = *(const float4*)&sH[1][kq * 4];
    float4 c = *(const float4*)&sH[2][kq * 4];
    float4 e = *(const float4*)&sH[3][kq * 4];
    acc0 += w.x * a.x + w.y * a.y + w.z * a.z + w.w * a.w;
    acc1 += w.x * b.x + w.y * b.y + w.z * b.z + w.w * b.w;
    acc2 += w.x * c.x + w.y * c.y + w.z * c.z + w.w * c.w;
    acc3 += w.x * e.x + w.y * e.y + w.z * e.z + w.w * e.w;
  }
  const float bias = bq[m];
  query[(size_t)(b0 + 0) * MDIM + m] = __float2bfloat16(acc0 + bias);
  query[(size_t)(b0 + 1) * MDIM + m] = __float2bfloat16(acc1 + bias);
  query[(size_t)(b0 + 2) * MDIM + m] = __float2bfloat16(acc2 + bias);
  query[(size_t)(b0 + 3) * MDIM + m] = __float2bfloat16(acc3 + bias);
}

// ---------------------------------------------------------------------------
// K3: block-cooperative subtree walker.
// Block = 4 waves = 64 b  x  one depth-5 subtree (S5 = blockIdx.x % 64).
// Per tile (16 keys x 64 b): keys staged in LDS (XOR-swizzled, dbuf),
// each wave does 4 MFMAs (A=keys, B=its 16-b query frag):
//   D row = key = (lane>>4)*4+reg  -> lane's f32x4 = one sibling quad
//   D col = b   = lane&15          -> thread-local log-softmax, NO shuffles.
// Parent chain + store-transpose via 3 aliased per-wave LDS cum buffers
// (layout [b=c][key], stride 20 dw):  bufA: d1->d3->d5, bufB: d2->d4->d6,
// bufC: d7 scratch. Parent of child row r is parent row 4u+(r>>2) (same b)
// -> one ds_read_b32. Flush: ds_read_b128 + global_store_dwordx4
// (16 rows x 64B, consecutive d7 tiles merge to full lines in L2).
// Grid ordered subtree-fastest: XCD = blockIdx%8 = S5%8 pins 8 subtrees
// (~770KB keys) per XCD L2 -> key reads are L2 hits.
// ---------------------------------------------------------------------------
#define CSTR 20   // cum-buf row stride (dwords); conflict-free per-phase

__device__ __forceinline__ void tile_step(
    const __hip_bfloat16* __restrict__ keys, float* __restrict__ sK, int& sbuf,
    int nextBase, const bf16x8 qf[4], const float* parentBuf, int u,
    float* cumBuf, float* __restrict__ outPtr, int span, bool doFlush,
    bool only16, int lane, int w) {
  const int hi = lane >> 4, c = lane & 15;

  // prefetch next key tile into regs (linear source read, coalesced 256B/row)
  float4 stg;
  int srow = 0, scolB = 0;
  const bool hasNext = nextBase >= 0;
  if (hasNext) {
    srow  = w * 4 + hi;
    scolB = c * 16;
    stg = *reinterpret_cast<const float4*>(
        reinterpret_cast<const char*>(keys) + (size_t)(nextBase + srow) * 256 + scolB);
  }

  // A-frags from staged (swizzled) LDS tile + MFMA
  const char* kt = reinterpret_cast<const char*>(sK) + sbuf * 4096;
  f32x4 acc = {};
#pragma unroll
  for (int kf = 0; kf < 4; ++kf) {
    const int colB = (kf * 64 + hi * 16) ^ ((c & 7) << 4);
    bf16x8 af = *reinterpret_cast<const bf16x8*>(kt + c * 256 + colB);
    acc = __builtin_amdgcn_mfma_f32_16x16x32_bf16(af, qf[kf], acc, 0, 0, 0);
  }

  // thread-local group-of-4 log-softmax
  const float mx = fmaxf(fmaxf(acc[0], acc[1]), fmaxf(acc[2], acc[3]));
  const float lse = mx + __logf(__expf(acc[0] - mx) + __expf(acc[1] - mx) +
                                __expf(acc[2] - mx) + __expf(acc[3] - mx));
  float par = 0.f;
  if (parentBuf) par = parentBuf[c * CSTR + 4 * u + hi];
  f32x4 cum;
  cum[0] = acc[0] - lse + par;
  cum[1] = acc[1] - lse + par;
  cum[2] = acc[2] - lse + par;
  cum[3] = acc[3] - lse + par;

  // write cum tile to per-wave LDS buffer: [b=c][key hi*4..+3]
  *reinterpret_cast<f32x4*>(cumBuf + c * CSTR + hi * 4) = cum;

  // flush coalesced: lane -> (b = lane>>2, keyquad = lane&3)
  if (doFlush) {
    if (only16) {  // depth-1: 4 nodes, 16 b rows
      if (lane < 16) {
        f32x4 v = *reinterpret_cast<const f32x4*>(cumBuf + lane * CSTR);
        float4 o; o.x = v[0]; o.y = v[1]; o.z = v[2]; o.w = v[3];
        *reinterpret_cast<float4*>(outPtr + (size_t)lane * span) = o;
      }
    } else {
      const int b16 = lane >> 2, q = lane & 3;
      f32x4 v = *reinterpret_cast<const f32x4*>(cumBuf + b16 * CSTR + q * 4);
      float4 o; o.x = v[0]; o.y = v[1]; o.z = v[2]; o.w = v[3];
      *reinterpret_cast<float4*>(outPtr + (size_t)b16 * span + q * 4) = o;
    }
  }

  // write staged tile to the other LDS buffer (swizzled dest), then barrier
  if (hasNext) {
    char* dst = reinterpret_cast<char*>(sK) + (sbuf ^ 1) * 4096;
    *reinterpret_cast<float4*>(dst + srow * 256 + (scolB ^ ((srow & 7) << 4))) = stg;
  }
  __syncthreads();
  sbuf ^= 1;
}

__global__ __launch_bounds__(256) void k_tree(const __hip_bfloat16* __restrict__ keys,
                                              const __hip_bfloat16* __restrict__ query,
                                              float* __restrict__ out, int B) {
  __shared__ __align__(16) float sKeys[2][1024];        // 2 x 4KB key tiles
  __shared__ __align__(16) float sCum[4][3][16 * CSTR]; // 4 waves x 3 bufs

  const int tid  = threadIdx.x;
  const int lane = tid & 63;
  const int w    = tid >> 6;
  const int hi   = lane >> 4, c = lane & 15;

  const int S5  = blockIdx.x & 63;        // depth-5 subtree (XCD = S5%8)
  const int bg  = blockIdx.x >> 6;        // batch group (64 b)
  const int T4  = S5 >> 2;
  const int T3  = S5 >> 4;
  const int b0w = bg * 64 + w * 16;

  float* bufA = &sCum[w][0][0];
  float* bufB = &sCum[w][1][0];
  float* bufC = &sCum[w][2][0];

  // query B-frags (held in regs for all 25 tiles): row b0w+c, chunk hi
  bf16x8 qf[4];
  {
    const __hip_bfloat16* qrow = query + (size_t)(b0w + c) * MDIM;
#pragma unroll
    for (int kf = 0; kf < 4; ++kf)
      qf[kf] = *reinterpret_cast<const bf16x8*>(qrow + kf * 32 + hi * 8);
  }

  // prologue: stage key tile 0 (base 0) into sKeys[0]
  {
    const int srow = w * 4 + hi, scolB = c * 16;
    float4 v = *reinterpret_cast<const float4*>(
        reinterpret_cast<const char*>(keys) + (size_t)srow * 256 + scolB);
    *reinterpret_cast<float4*>(reinterpret_cast<char*>(&sKeys[0][0]) +
                               srow * 256 + (scolB ^ ((srow & 7) << 4))) = v;
    __syncthreads();
  }

  int sbuf = 0;
  // t0: d1 (keys 0..15; quad 0 = real d1 nodes)
  tile_step(keys, &sKeys[0][0], sbuf, 4, qf, nullptr, 0, bufA,
            out + (size_t)b0w * 4, 4, S5 == 0, true, lane, w);
  // t1: d2 (base 4)
  tile_step(keys, &sKeys[0][0], sbuf, 20 + 16 * T3, qf, bufA, 0, bufB,
            out + (size_t)4 * B + (size_t)b0w * 16, 16, S5 == 0, false, lane, w);
  // t2: d3 (tile T3)
  tile_step(keys, &sKeys[0][0], sbuf, 84 + 16 * T4, qf, bufB, T3, bufA,
            out + (size_t)20 * B + (size_t)b0w * 64 + 16 * T3, 64,
            (S5 & 15) == 0, false, lane, w);
  // t3: d4 (tile T4)
  tile_step(keys, &sKeys[0][0], sbuf, 340 + 16 * S5, qf, bufA, T4 & 3, bufB,
            out + (size_t)84 * B + (size_t)b0w * 256 + 16 * T4, 256,
            (S5 & 3) == 0, false, lane, w);
  // t4: d5 (tile S5)
  tile_step(keys, &sKeys[0][0], sbuf, 1364 + 16 * (4 * S5), qf, bufB, S5 & 3, bufA,
            out + (size_t)340 * B + (size_t)b0w * 1024 + 16 * S5, 1024,
            true, false, lane, w);

#pragma unroll
  for (int u5 = 0; u5 < 4; ++u5) {
    const int T6 = 4 * S5 + u5;
    // d6 tile T6; next = its first d7 child
    tile_step(keys, &sKeys[0][0], sbuf, 5460 + 16 * (4 * T6), qf, bufA, u5, bufB,
              out + (size_t)1364 * B + (size_t)b0w * 4096 + 16 * T6, 4096,
              true, false, lane, w);
#pragma unroll
    for (int u6 = 0; u6 < 4; ++u6) {
      const int T7 = 4 * T6 + u6;
      int nb;
      if (u6 < 3)      nb = 5460 + 16 * (T7 + 1);
      else if (u5 < 3) nb = 1364 + 16 * (4 * S5 + u5 + 1);
      else             nb = -1;
      tile_step(keys, &sKeys[0][0], sbuf, nb, qf, bufB, u6, bufC,
                out + (size_t)5460 * B + (size_t)b0w * 16384 + 16 * T7, 16384,
                true, false, lane, w);
    }
  }
}

// ---------------------------------------------------------------------------
extern "C" void kernel_launch(void* const* d_in, const int* in_sizes, int n_in,
                              void* d_out, int out_size, void* d_ws, size_t ws_size,
                              hipStream_t stream) {
  const float* hidden = (const float*)d_in[0];
  const float* Wq     = (const float*)d_in[1];
  const float* bq     = (const float*)d_in[2];
  const float* states = (const float*)d_in[3];
  const float* Wk     = (const float*)d_in[4];
  const float* bk     = (const float*)d_in[5];
  float* out = (float*)d_out;
  const int B = in_sizes[0] / CDIM;  // 4096

  __hip_bfloat16* keys  = (__hip_bfloat16*)d_ws;        // NKEYS*128 bf16 = 5.6 MB
  __hip_bfloat16* query = keys + (size_t)NKEYS * MDIM;  // B*128 bf16 = 1 MB

  k_keys<<<NKEYS / 4, 128, 0, stream>>>(states, Wk, bk, keys);
  k_query<<<B / 4, 128, 0, stream>>>(hidden, Wq, bq, query);

  // grid: subtree-fastest (XCD pinning), 64 subtrees x B/64 batch groups
  k_tree<<<(B / 64) * 64, 256, 0, stream>>>(keys, query, out, B);
}